// Round 14
// baseline (299.954 us; speedup 1.0000x reference)
//
#include <hip/hip_runtime.h>

typedef __attribute__((ext_vector_type(8))) short short8;
typedef __attribute__((ext_vector_type(4))) short short4v;
typedef __attribute__((ext_vector_type(4))) float float4v;

#define DEV static __device__ __forceinline__

DEV float b2f(unsigned short u) { return __uint_as_float(((unsigned)u) << 16); }
DEV unsigned short f2b(float f) {
  return __builtin_bit_cast(unsigned short, static_cast<__bf16>(f));
}

#define LOG2E 1.44269504088896340736f
#define QSCALE 0.17677669529663687f  // 32^-0.5

// ws layout (2-byte units):
// [0, 49152)      qkv_w bf16  [384][128]  (out_col, k) k-contig; W_q rows pre-scaled by QSCALE*LOG2E
// [49152, 65536)  proj_w bf16 [128][128]
// [65536, 81920)  biasM bf16  [4][64 q-row][64 key] row-major, pre-scaled by LOG2E (fallback path)
// [81920, +33.5M) comb2 bf16 [1024 wm][4 h][4 ci][4 ri][64 lane][4 j] = (mask+bias)*LOG2E (EXPANDED)
#define COMB2_OFF 81920
#define COMB2_SHORTS (1024u * 4u * 4096u)

__global__ void prep_kernel(const float* __restrict__ qkvw, const float* __restrict__ projw,
                            const float* __restrict__ btab, const int* __restrict__ ridx,
                            unsigned short* __restrict__ ws) {
  int t = blockIdx.x * blockDim.x + threadIdx.x;
  int nt = gridDim.x * blockDim.x;
  for (int i = t; i < 49152; i += nt) {
    float v = qkvw[i];
    if (i < 16384) v *= QSCALE * LOG2E;  // W_q rows pre-scaled (softmax exp base-2 fold)
    ws[i] = f2b(v);
  }
  for (int i = t; i < 16384; i += nt) ws[49152 + i] = f2b(projw[i]);
  for (int i = t; i < 16384; i += nt) {
    int h = i >> 12, r = i & 4095;
    ws[65536 + i] = f2b(btab[ridx[r] * 4 + h] * LOG2E);
  }
}

// comb2[wm][h][ci][ri][lane][j] = bf16((mask[wm][row][key] + bias_h[row][key]) * LOG2E)
// with row = 16*ri + (lane&15), key = 16*ci + 4*(lane>>4) + j  -> S-loop C is one 8B coalesced load
__global__ void prep2_kernel(const float* __restrict__ mask, const float* __restrict__ btab,
                             const int* __restrict__ ridx, unsigned short* __restrict__ comb) {
  int wm = blockIdx.x, tid = threadIdx.x;
  const float* mrow = mask + (size_t)wm * 4096;
  unsigned short* cb = comb + (size_t)wm * 16384;
  for (int it = 0; it < 16; ++it) {
    int q4 = it * 256 + tid;            // short4 index 0..4095
    int lane = q4 & 63, ri = (q4 >> 6) & 3, ci = (q4 >> 8) & 3, h = q4 >> 10;
    int l15 = lane & 15, g = lane >> 4;
    int row = 16 * ri + l15;
    short4v v;
#pragma unroll
    for (int j = 0; j < 4; ++j) {
      int key = 16 * ci + 4 * g + j;
      float bias = btab[ridx[row * 64 + key] * 4 + h];
      v[j] = (short)f2b((mrow[row * 64 + key] + bias) * LOG2E);
    }
    *(short4v*)&cb[q4 * 4] = v;
  }
}

#define MFMA32 __builtin_amdgcn_mfma_f32_16x16x32_bf16
#define MFMA16 __builtin_amdgcn_mfma_f32_16x16x16bf16_1k

// ============================ EXPANDED (occ 4) ==============================
__global__ __launch_bounds__(256, 4)
void win_attn_x4(const float* __restrict__ x, const float* __restrict__ qkv_b,
                 const float* __restrict__ proj_b, const unsigned short* __restrict__ ws,
                 float* __restrict__ out) {
  // LDS (32 KB): [0,8192)      x tile [64][128] bf16, swizzled (later attn_out)
  //              [8192,16384)  V tiles, 4 heads x [32 d][64 key] bf16, swizzled
  __shared__ short sm[16384];

  const int b = blockIdx.x;
  const int tid = threadIdx.x;
  const int h = tid >> 6;       // wave id == head
  const int lane = tid & 63;
  const int l15 = lane & 15;
  const int g = lane >> 4;
  const int g1 = g & 1, g2 = g >> 1;
  const int wm = b & 1023;

  // ---------------- phase 0: stage x only ------------------------------------
  {
    const float4* xw = (const float4*)(x + (size_t)b * 8192);
#pragma unroll
    for (int it = 0; it < 4; ++it) {
      int c = it * 256 + tid;           // 8-elem chunk 0..1023
      int row = c >> 4, ch = c & 15;
      float4 a0 = xw[c * 2], a1 = xw[c * 2 + 1];
      short8 v;
      v[0] = (short)f2b(a0.x); v[1] = (short)f2b(a0.y);
      v[2] = (short)f2b(a0.z); v[3] = (short)f2b(a0.w);
      v[4] = (short)f2b(a1.x); v[5] = (short)f2b(a1.y);
      v[6] = (short)f2b(a1.z); v[7] = (short)f2b(a1.w);
      *(short8*)&sm[row * 128 + ((ch ^ (row & 7)) << 3)] = v;
    }
  }
  __syncthreads();

#define LDA(kt, ri) (*(const short8*)&sm[(16 * (ri) + l15) * 128 + ((((kt)*4 + g) ^ (l15 & 7)) << 3)])

  short8 kp8[4], qp8[4];

  // ---------------- pass k: k^T = Wk x^T + bk (swapped) ----------------------
  {
    float4v acc[2][4];
#pragma unroll
    for (int dc = 0; dc < 2; ++dc) {
      float4v bk = *(const float4v*)&qkv_b[128 + h * 32 + dc * 16 + 4 * g];
#pragma unroll
      for (int ci = 0; ci < 4; ++ci)
#pragma unroll
        for (int j = 0; j < 4; ++j) acc[dc][ci][j] = bk[j];
    }
#pragma unroll
    for (int kt = 0; kt < 4; ++kt) {
      short8 af[4];
#pragma unroll
      for (int ri = 0; ri < 4; ++ri) af[ri] = LDA(kt, ri);
#pragma unroll
      for (int dc = 0; dc < 2; ++dc) {
        short8 wk = *(const short8*)&ws[(128 + h * 32 + dc * 16 + l15) * 128 + kt * 32 + g * 8];
#pragma unroll
        for (int ci = 0; ci < 4; ++ci) acc[dc][ci] = MFMA32(wk, af[ci], acc[dc][ci], 0, 0, 0);
      }
    }
#pragma unroll
    for (int ci = 0; ci < 4; ++ci)
#pragma unroll
      for (int dc = 0; dc < 2; ++dc)
#pragma unroll
        for (int j = 0; j < 4; ++j) kp8[ci][4 * dc + j] = (short)f2b(acc[dc][ci][j]);
  }

  // ---------------- pass v: v = x Wv^T + bv -> LDS (same-wave) ---------------
  {
    float4v acc[2][4];
#pragma unroll
    for (int dt = 0; dt < 2; ++dt) {
      float bv = qkv_b[256 + h * 32 + dt * 16 + l15];
#pragma unroll
      for (int ci = 0; ci < 4; ++ci)
#pragma unroll
        for (int j = 0; j < 4; ++j) acc[dt][ci][j] = bv;
    }
#pragma unroll
    for (int kt = 0; kt < 4; ++kt) {
      short8 af[4];
#pragma unroll
      for (int ri = 0; ri < 4; ++ri) af[ri] = LDA(kt, ri);
#pragma unroll
      for (int dt = 0; dt < 2; ++dt) {
        short8 wv = *(const short8*)&ws[(256 + h * 32 + dt * 16 + l15) * 128 + kt * 32 + g * 8];
#pragma unroll
        for (int ci = 0; ci < 4; ++ci) acc[dt][ci] = MFMA32(af[ci], wv, acc[dt][ci], 0, 0, 0);
      }
    }
    // store V[key][d] transposed as Vlds[d][key], swizzled; read back only by this wave
#pragma unroll
    for (int dt = 0; dt < 2; ++dt) {
      int d = 16 * dt + l15;
#pragma unroll
      for (int ci = 0; ci < 4; ++ci) {
        int ch = (2 * ci + g2) ^ (d & 7);
        short4v pv;
#pragma unroll
        for (int j = 0; j < 4; ++j) pv[j] = (short)f2b(acc[dt][ci][j]);
        *(short4v*)&sm[8192 + h * 2048 + d * 64 + (ch << 3) + 4 * g1] = pv;
      }
    }
  }

  // ---------------- pass q: q^T = (Wq' x^T) + bq*QSCALE*LOG2E (swapped) ------
  {
    float4v acc[2][4];
#pragma unroll
    for (int dc = 0; dc < 2; ++dc) {
      float4v bb = *(const float4v*)&qkv_b[h * 32 + dc * 16 + 4 * g];
#pragma unroll
      for (int ri = 0; ri < 4; ++ri)
#pragma unroll
        for (int j = 0; j < 4; ++j) acc[dc][ri][j] = bb[j] * (QSCALE * LOG2E);
    }
#pragma unroll
    for (int kt = 0; kt < 4; ++kt) {
      short8 af[4];
#pragma unroll
      for (int ri = 0; ri < 4; ++ri) af[ri] = LDA(kt, ri);
#pragma unroll
      for (int dc = 0; dc < 2; ++dc) {
        short8 w = *(const short8*)&ws[(h * 32 + dc * 16 + l15) * 128 + kt * 32 + g * 8];
#pragma unroll
        for (int ri = 0; ri < 4; ++ri) acc[dc][ri] = MFMA32(w, af[ri], acc[dc][ri], 0, 0, 0);
      }
    }
#pragma unroll
    for (int ri = 0; ri < 4; ++ri)
#pragma unroll
      for (int dc = 0; dc < 2; ++dc)
#pragma unroll
        for (int j = 0; j < 4; ++j) qp8[ri][4 * dc + j] = (short)f2b(acc[dc][ri][j]);
  }

  // ---------------- S' = K Q^T (K=32) + comb2, exp2, PV (K=16 from LDS V) ----
  const unsigned short* cb = ws + COMB2_OFF + ((size_t)(wm * 4 + h)) * 4096;
  float4v ot[2][4];
#pragma unroll
  for (int dt = 0; dt < 2; ++dt)
#pragma unroll
    for (int ri = 0; ri < 4; ++ri) { ot[dt][ri][0]=0.f; ot[dt][ri][1]=0.f; ot[dt][ri][2]=0.f; ot[dt][ri][3]=0.f; }
  float rs[4];
#pragma unroll
  for (int ri = 0; ri < 4; ++ri) {
    float sum = 0.f;
#pragma unroll
    for (int ci = 0; ci < 4; ++ci) {
      short4v cm = *(const short4v*)&cb[(ci * 4 + ri) * 256 + lane * 4];
      float4v c;
#pragma unroll
      for (int j = 0; j < 4; ++j) c[j] = b2f((unsigned short)cm[j]);
      c = MFMA32(kp8[ci], qp8[ri], c, 0, 0, 0);
      short4v pb;
#pragma unroll
      for (int j = 0; j < 4; ++j) {
        float p = exp2f(c[j]);
        sum += p;
        pb[j] = (short)f2b(p);
      }
#pragma unroll
      for (int dt = 0; dt < 2; ++dt) {
        int d = 16 * dt + l15;
        int ch = (2 * ci + g2) ^ (d & 7);
        short4v vf = *(const short4v*)&sm[8192 + h * 2048 + d * 64 + (ch << 3) + 4 * g1];
        ot[dt][ri] = MFMA16(vf, pb, ot[dt][ri], 0, 0, 0);
      }
    }
    sum += __shfl_xor(sum, 16);
    sum += __shfl_xor(sum, 32);
    rs[ri] = __builtin_amdgcn_rcpf(sum);
  }

  __syncthreads();  // all waves past q-pass: x tile dead everywhere
#pragma unroll
  for (int dt = 0; dt < 2; ++dt) {
    int ch = 4 * h + 2 * dt + g2;
#pragma unroll
    for (int ri = 0; ri < 4; ++ri) {
      int row = 16 * ri + l15;
      short4v pv;
#pragma unroll
      for (int j = 0; j < 4; ++j) pv[j] = (short)f2b(ot[dt][ri][j] * rs[ri]);
      *(short4v*)&sm[row * 128 + ((ch ^ (row & 7)) << 3) + 4 * g1] = pv;
    }
  }
  __syncthreads();

  // ---------------- output projection (swapped), C init = proj_b -------------
  float4v po[2][4];
#pragma unroll
  for (int oc = 0; oc < 2; ++oc) {
    float4v pb4 = *(const float4v*)&proj_b[h * 32 + oc * 16 + 4 * g];
#pragma unroll
    for (int ri = 0; ri < 4; ++ri)
#pragma unroll
      for (int j = 0; j < 4; ++j) po[oc][ri][j] = pb4[j];
  }
#pragma unroll
  for (int kt = 0; kt < 4; ++kt) {
    short8 af[4];
#pragma unroll
    for (int ri = 0; ri < 4; ++ri) af[ri] = LDA(kt, ri);
#pragma unroll
    for (int oc = 0; oc < 2; ++oc) {
      short8 w = *(const short8*)&ws[49152 + (h * 32 + oc * 16 + l15) * 128 + kt * 32 + g * 8];
#pragma unroll
      for (int ri = 0; ri < 4; ++ri)
        po[oc][ri] = MFMA32(w, af[ri], po[oc][ri], 0, 0, 0);
    }
  }
  float* ob = out + (size_t)b * 8192;
#pragma unroll
  for (int oc = 0; oc < 2; ++oc)
#pragma unroll
    for (int ri = 0; ri < 4; ++ri) {
      int row = 16 * ri + l15;
      float4 o = make_float4(po[oc][ri][0], po[oc][ri][1], po[oc][ri][2], po[oc][ri][3]);
      *(float4*)&ob[row * 128 + h * 32 + oc * 16 + 4 * g] = o;
    }
#undef LDA
}

// ============================ FALLBACK (R12 exact, occ 3) ===================
__global__ __launch_bounds__(256, 3)
void win_attn_fb(const float* __restrict__ x, const float* __restrict__ mask,
                 const float* __restrict__ qkv_b, const float* __restrict__ proj_b,
                 const unsigned short* __restrict__ ws, float* __restrict__ out) {
  __shared__ short sm[24576];
  const int b = blockIdx.x;
  const int tid = threadIdx.x;
  const int h = tid >> 6;
  const int lane = tid & 63;
  const int l15 = lane & 15;
  const int g = lane >> 4;
  const int g1 = g & 1, g2 = g >> 1;
  const int wm = b & 1023;
  {
    const float4* xw = (const float4*)(x + (size_t)b * 8192);
#pragma unroll
    for (int it = 0; it < 4; ++it) {
      int c = it * 256 + tid;
      int row = c >> 4, ch = c & 15;
      float4 a0 = xw[c * 2], a1 = xw[c * 2 + 1];
      short8 v;
      v[0] = (short)f2b(a0.x); v[1] = (short)f2b(a0.y);
      v[2] = (short)f2b(a0.z); v[3] = (short)f2b(a0.w);
      v[4] = (short)f2b(a1.x); v[5] = (short)f2b(a1.y);
      v[6] = (short)f2b(a1.z); v[7] = (short)f2b(a1.w);
      *(short8*)&sm[row * 128 + ((ch ^ (row & 7)) << 3)] = v;
    }
    const float* mrow = mask + (size_t)wm * 4096;
    const unsigned short* bt = ws + 65536 + h * 4096;
    short* cs = &sm[8192 + h * 4096];
#pragma unroll 4
    for (int it = 0; it < 16; ++it) {
      int fi = it * 64 + lane;
      int row = fi >> 4, j0 = (fi & 15) << 2;
      float4 m4 = *(const float4*)&mrow[fi * 4];
      const unsigned short* bp = bt + row * 64 + j0;
      short4v v;
      v[0] = (short)f2b(__builtin_fmaf(m4.x, LOG2E, b2f(bp[0])));
      v[1] = (short)f2b(__builtin_fmaf(m4.y, LOG2E, b2f(bp[1])));
      v[2] = (short)f2b(__builtin_fmaf(m4.z, LOG2E, b2f(bp[2])));
      v[3] = (short)f2b(__builtin_fmaf(m4.w, LOG2E, b2f(bp[3])));
      *(short4v*)&cs[row * 64 + (((j0 >> 3) ^ (row & 7)) << 3) + (j0 & 7)] = v;
    }
  }
  __syncthreads();
#define LDA(kt, ri) (*(const short8*)&sm[(16 * (ri) + l15) * 128 + ((((kt)*4 + g) ^ (l15 & 7)) << 3)])
  short8 kp8[4], qp8[4], vp8[2][2];
  {
    float4v acck[2][4], accv[2][4];
#pragma unroll
    for (int dc = 0; dc < 2; ++dc) {
      float4v bk = *(const float4v*)&qkv_b[128 + h * 32 + dc * 16 + 4 * g];
      float bv = qkv_b[256 + h * 32 + dc * 16 + l15];
#pragma unroll
      for (int ri = 0; ri < 4; ++ri)
#pragma unroll
        for (int j = 0; j < 4; ++j) { acck[dc][ri][j] = bk[j]; accv[dc][ri][j] = bv; }
    }
#pragma unroll
    for (int kt = 0; kt < 4; ++kt) {
      short8 af[4];
#pragma unroll
      for (int ri = 0; ri < 4; ++ri) af[ri] = LDA(kt, ri);
#pragma unroll
      for (int dc = 0; dc < 2; ++dc) {
        short8 wk = *(const short8*)&ws[(128 + h * 32 + dc * 16 + l15) * 128 + kt * 32 + g * 8];
#pragma unroll
        for (int ri = 0; ri < 4; ++ri) acck[dc][ri] = MFMA32(wk, af[ri], acck[dc][ri], 0, 0, 0);
      }
#pragma unroll
      for (int dt = 0; dt < 2; ++dt) {
        short8 wv = *(const short8*)&ws[(256 + h * 32 + dt * 16 + l15) * 128 + kt * 32 + g * 8];
#pragma unroll
        for (int ri = 0; ri < 4; ++ri) accv[dt][ri] = MFMA32(af[ri], wv, accv[dt][ri], 0, 0, 0);
      }
    }
#pragma unroll
    for (int ci = 0; ci < 4; ++ci)
#pragma unroll
      for (int dc = 0; dc < 2; ++dc)
#pragma unroll
        for (int j = 0; j < 4; ++j) kp8[ci][4 * dc + j] = (short)f2b(acck[dc][ci][j]);
#pragma unroll
    for (int dt = 0; dt < 2; ++dt)
#pragma unroll
      for (int ci = 0; ci < 4; ++ci)
#pragma unroll
        for (int j = 0; j < 4; ++j)
          vp8[dt][ci >> 1][4 * (ci & 1) + j] = (short)f2b(accv[dt][ci][j]);
  }
  {
    float4v acc[2][4];
#pragma unroll
    for (int dc = 0; dc < 2; ++dc) {
      float4v bb = *(const float4v*)&qkv_b[h * 32 + dc * 16 + 4 * g];
#pragma unroll
      for (int ri = 0; ri < 4; ++ri)
#pragma unroll
        for (int j = 0; j < 4; ++j) acc[dc][ri][j] = bb[j] * (QSCALE * LOG2E);
    }
#pragma unroll
    for (int kt = 0; kt < 4; ++kt) {
      short8 af[4];
#pragma unroll
      for (int ri = 0; ri < 4; ++ri) af[ri] = LDA(kt, ri);
#pragma unroll
      for (int dc = 0; dc < 2; ++dc) {
        short8 w = *(const short8*)&ws[(h * 32 + dc * 16 + l15) * 128 + kt * 32 + g * 8];
#pragma unroll
        for (int ri = 0; ri < 4; ++ri) acc[dc][ri] = MFMA32(w, af[ri], acc[dc][ri], 0, 0, 0);
      }
    }
#pragma unroll
    for (int ri = 0; ri < 4; ++ri)
#pragma unroll
      for (int dc = 0; dc < 2; ++dc)
#pragma unroll
        for (int j = 0; j < 4; ++j) qp8[ri][4 * dc + j] = (short)f2b(acc[dc][ri][j]);
  }
  const short* cs = &sm[8192 + h * 4096];
  float4v ot[2][4];
#pragma unroll
  for (int dt = 0; dt < 2; ++dt)
#pragma unroll
    for (int ri = 0; ri < 4; ++ri) { ot[dt][ri][0]=0.f; ot[dt][ri][1]=0.f; ot[dt][ri][2]=0.f; ot[dt][ri][3]=0.f; }
  float rs[4];
#pragma unroll
  for (int ri = 0; ri < 4; ++ri) {
    int row = 16 * ri + l15;
    float sum = 0.f;
    short4v pb[4];
#pragma unroll
    for (int ci = 0; ci < 4; ++ci) {
      short4v cm = *(const short4v*)&cs[row * 64 + (((2 * ci + g2) ^ (row & 7)) << 3) + 4 * g1];
      float4v c;
#pragma unroll
      for (int j = 0; j < 4; ++j) c[j] = b2f((unsigned short)cm[j]);
      c = MFMA32(kp8[ci], qp8[ri], c, 0, 0, 0);
#pragma unroll
      for (int j = 0; j < 4; ++j) {
        float p = exp2f(c[j]);
        sum += p;
        pb[ci][j] = (short)f2b(p);
      }
    }
#pragma unroll
    for (int c2 = 0; c2 < 2; ++c2) {
      short8 pb8 = __builtin_shufflevector(pb[2 * c2], pb[2 * c2 + 1], 0, 1, 2, 3, 4, 5, 6, 7);
      ot[0][ri] = MFMA32(vp8[0][c2], pb8, ot[0][ri], 0, 0, 0);
      ot[1][ri] = MFMA32(vp8[1][c2], pb8, ot[1][ri], 0, 0, 0);
    }
    sum += __shfl_xor(sum, 16);
    sum += __shfl_xor(sum, 32);
    rs[ri] = __builtin_amdgcn_rcpf(sum);
  }
  __syncthreads();
#pragma unroll
  for (int dt = 0; dt < 2; ++dt) {
    int ch = 4 * h + 2 * dt + g2;
#pragma unroll
    for (int ri = 0; ri < 4; ++ri) {
      int row = 16 * ri + l15;
      short4v pv;
#pragma unroll
      for (int j = 0; j < 4; ++j) pv[j] = (short)f2b(ot[dt][ri][j] * rs[ri]);
      *(short4v*)&sm[row * 128 + ((ch ^ (row & 7)) << 3) + 4 * g1] = pv;
    }
  }
  __syncthreads();
  float4v po[2][4];
#pragma unroll
  for (int oc = 0; oc < 2; ++oc) {
    float4v pb4 = *(const float4v*)&proj_b[h * 32 + oc * 16 + 4 * g];
#pragma unroll
    for (int ri = 0; ri < 4; ++ri)
#pragma unroll
      for (int j = 0; j < 4; ++j) po[oc][ri][j] = pb4[j];
  }
#pragma unroll
  for (int kt = 0; kt < 4; ++kt) {
    short8 af[4];
#pragma unroll
    for (int ri = 0; ri < 4; ++ri) af[ri] = LDA(kt, ri);
#pragma unroll
    for (int oc = 0; oc < 2; ++oc) {
      short8 w = *(const short8*)&ws[49152 + (h * 32 + oc * 16 + l15) * 128 + kt * 32 + g * 8];
#pragma unroll
      for (int ri = 0; ri < 4; ++ri)
        po[oc][ri] = MFMA32(w, af[ri], po[oc][ri], 0, 0, 0);
    }
  }
  float* ob = out + (size_t)b * 8192;
#pragma unroll
  for (int oc = 0; oc < 2; ++oc)
#pragma unroll
    for (int ri = 0; ri < 4; ++ri) {
      int row = 16 * ri + l15;
      float4 o = make_float4(po[oc][ri][0], po[oc][ri][1], po[oc][ri][2], po[oc][ri][3]);
      *(float4*)&ob[row * 128 + h * 32 + oc * 16 + 4 * g] = o;
    }
#undef LDA
}

extern "C" void kernel_launch(void* const* d_in, const int* in_sizes, int n_in,
                              void* d_out, int out_size, void* d_ws, size_t ws_size,
                              hipStream_t stream) {
  const float* x      = (const float*)d_in[0];
  const float* mask   = (const float*)d_in[1];
  const float* qkv_w  = (const float*)d_in[2];
  const float* qkv_b  = (const float*)d_in[3];
  const float* proj_w = (const float*)d_in[4];
  const float* proj_b = (const float*)d_in[5];
  const float* btab   = (const float*)d_in[6];
  const int*   ridx   = (const int*)d_in[7];
  unsigned short* ws  = (unsigned short*)d_ws;
  float* out = (float*)d_out;

  const bool expanded = ws_size >= (size_t)(COMB2_OFF + COMB2_SHORTS) * 2u;

  hipLaunchKernelGGL(prep_kernel, dim3(64), dim3(256), 0, stream, qkv_w, proj_w, btab, ridx, ws);
  if (expanded) {
    hipLaunchKernelGGL(prep2_kernel, dim3(1024), dim3(256), 0, stream, mask, btab, ridx, ws + COMB2_OFF);
    hipLaunchKernelGGL(win_attn_x4, dim3(8192), dim3(256), 0, stream,
                       x, qkv_b, proj_b, ws, out);
  } else {
    hipLaunchKernelGGL(win_attn_fb, dim3(8192), dim3(256), 0, stream,
                       x, mask, qkv_b, proj_b, ws, out);
  }
}

// Round 15
// 202.003 us; speedup vs baseline: 1.4849x; 1.4849x over previous
//
#include <hip/hip_runtime.h>

typedef __attribute__((ext_vector_type(8))) short short8;
typedef __attribute__((ext_vector_type(4))) short short4v;
typedef __attribute__((ext_vector_type(4))) float float4v;

#define DEV static __device__ __forceinline__

DEV float b2f(unsigned short u) { return __uint_as_float(((unsigned)u) << 16); }
DEV unsigned short f2b(float f) {
  return __builtin_bit_cast(unsigned short, static_cast<__bf16>(f));
}

#define LOG2E 1.44269504088896340736f
#define QSCALE 0.17677669529663687f  // 32^-0.5

// ws layout (2-byte units):
// [0, 65536)      weights bf16, lane-ordered fragments:
//                 [m:{q,k,v,proj}][h][kt][dc][lane][8]  (each fragment = contiguous 1KB)
//                 m=0 (W_q) pre-scaled by QSCALE*LOG2E
// [65536, 81920)  biasM bf16 [4][64 q-row][64 key] row-major, pre-scaled by LOG2E
__global__ void prep_kernel(const float* __restrict__ qkvw, const float* __restrict__ projw,
                            const float* __restrict__ btab, const int* __restrict__ ridx,
                            unsigned short* __restrict__ ws) {
  int t = blockIdx.x * blockDim.x + threadIdx.x;
  int nt = gridDim.x * blockDim.x;
  for (int i = t; i < 65536; i += nt) {
    int m = i >> 14, r = i & 16383;
    int e = r & 7, lane = (r >> 3) & 63, dc = (r >> 9) & 1, kt = (r >> 10) & 3, h = r >> 12;
    int row = h * 32 + dc * 16 + (lane & 15);
    int col = kt * 32 + (lane >> 4) * 8 + e;
    float v;
    if (m == 3) {
      v = projw[row * 128 + col];
    } else {
      v = qkvw[(m * 128 + row) * 128 + col];
      if (m == 0) v *= QSCALE * LOG2E;
    }
    ws[i] = f2b(v);
  }
  for (int i = t; i < 16384; i += nt) {
    int h = i >> 12, r = i & 4095;
    ws[65536 + i] = f2b(btab[ridx[r] * 4 + h] * LOG2E);
  }
}

#define MFMA32 __builtin_amdgcn_mfma_f32_16x16x32_bf16

__global__ __launch_bounds__(256, 3)
void win_attn_kernel(const float* __restrict__ x, const float* __restrict__ mask,
                     const float* __restrict__ qkv_b, const float* __restrict__ proj_b,
                     const unsigned short* __restrict__ ws, float* __restrict__ out) {
  // LDS: [0,8192)  x tile [64][128] bf16, swizzled (later attn_out)
  //      [8192 + h*4096)  combined (bias+mask)*LOG2E tile per head [64][64] bf16, swizzled
  __shared__ short sm[24576];

  const int b = blockIdx.x;
  const int tid = threadIdx.x;
  const int h = tid >> 6;       // wave id == head
  const int lane = tid & 63;
  const int l15 = lane & 15;
  const int g = lane >> 4;
  const int g1 = g & 1, g2 = g >> 1;
  const int wm = b & 1023;

  // ---------------- phase 0: stage x + combined (bias+mask)*LOG2E ------------
  {
    const float4* xw = (const float4*)(x + (size_t)b * 8192);
#pragma unroll
    for (int it = 0; it < 4; ++it) {
      int c = it * 256 + tid;           // 8-elem chunk 0..1023
      int row = c >> 4, ch = c & 15;
      float4 a0 = xw[c * 2], a1 = xw[c * 2 + 1];
      short8 v;
      v[0] = (short)f2b(a0.x); v[1] = (short)f2b(a0.y);
      v[2] = (short)f2b(a0.z); v[3] = (short)f2b(a0.w);
      v[4] = (short)f2b(a1.x); v[5] = (short)f2b(a1.y);
      v[6] = (short)f2b(a1.z); v[7] = (short)f2b(a1.w);
      *(short8*)&sm[row * 128 + ((ch ^ (row & 7)) << 3)] = v;
    }
    // combined = mask_wm*LOG2E + biasL_h (biasL pre-scaled), bf16, swizzled
    const float* mrow = mask + (size_t)wm * 4096;
    const unsigned short* bt = ws + 65536 + h * 4096;
    short* cs = &sm[8192 + h * 4096];
#pragma unroll 4
    for (int it = 0; it < 16; ++it) {
      int fi = it * 64 + lane;          // float4 idx 0..1023 within tile
      int row = fi >> 4, j0 = (fi & 15) << 2;
      float4 m4 = *(const float4*)&mrow[fi * 4];
      const unsigned short* bp = bt + row * 64 + j0;
      short4v v;
      v[0] = (short)f2b(__builtin_fmaf(m4.x, LOG2E, b2f(bp[0])));
      v[1] = (short)f2b(__builtin_fmaf(m4.y, LOG2E, b2f(bp[1])));
      v[2] = (short)f2b(__builtin_fmaf(m4.z, LOG2E, b2f(bp[2])));
      v[3] = (short)f2b(__builtin_fmaf(m4.w, LOG2E, b2f(bp[3])));
      *(short4v*)&cs[row * 64 + (((j0 >> 3) ^ (row & 7)) << 3) + (j0 & 7)] = v;
    }
  }
  __syncthreads();

  // x A/B-frag read: lane holds x[16ri+l15][32kt+8g .. +7]
#define LDA(kt, ri) (*(const short8*)&sm[(16 * (ri) + l15) * 128 + ((((kt)*4 + g) ^ (l15 & 7)) << 3)])
  // lane-ordered weight fragment: one contiguous 1KB read per wave
#define LW(mb, kt, dc) (*(const short8*)&ws[(mb) + (h << 12) + ((kt) << 10) + ((dc) << 9) + (lane << 3)])

  // K=32 MFMA fragments (slot-consistent concat of two K=16 halves):
  short8 kp8[4], qp8[4], vp8[2][2];

  // ---------------- merged pass k+v (shared af loads, kt looped) -------------
  {
    float4v acck[2][4], accv[2][4];
#pragma unroll
    for (int dc = 0; dc < 2; ++dc) {
      float4v bk = *(const float4v*)&qkv_b[128 + h * 32 + dc * 16 + 4 * g];
      float bv = qkv_b[256 + h * 32 + dc * 16 + l15];
#pragma unroll
      for (int ri = 0; ri < 4; ++ri)
#pragma unroll
        for (int j = 0; j < 4; ++j) { acck[dc][ri][j] = bk[j]; accv[dc][ri][j] = bv; }
    }
#pragma unroll 2
    for (int kt = 0; kt < 4; ++kt) {
      short8 af[4];
#pragma unroll
      for (int ri = 0; ri < 4; ++ri) af[ri] = LDA(kt, ri);
#pragma unroll
      for (int dc = 0; dc < 2; ++dc) {
        short8 wk = LW(16384, kt, dc);
#pragma unroll
        for (int ri = 0; ri < 4; ++ri) acck[dc][ri] = MFMA32(wk, af[ri], acck[dc][ri], 0, 0, 0);
      }
#pragma unroll
      for (int dt = 0; dt < 2; ++dt) {
        short8 wv = LW(32768, kt, dt);
#pragma unroll
        for (int ri = 0; ri < 4; ++ri) accv[dt][ri] = MFMA32(af[ri], wv, accv[dt][ri], 0, 0, 0);
      }
    }
#pragma unroll
    for (int ci = 0; ci < 4; ++ci)
#pragma unroll
      for (int dc = 0; dc < 2; ++dc)
#pragma unroll
        for (int j = 0; j < 4; ++j) kp8[ci][4 * dc + j] = (short)f2b(acck[dc][ci][j]);
#pragma unroll
    for (int dt = 0; dt < 2; ++dt)
#pragma unroll
      for (int ci = 0; ci < 4; ++ci)
#pragma unroll
        for (int j = 0; j < 4; ++j)
          vp8[dt][ci >> 1][4 * (ci & 1) + j] = (short)f2b(accv[dt][ci][j]);
  }

  // ---------------- pass q (kt looped) ---------------------------------------
  {
    float4v acc[2][4];
#pragma unroll
    for (int dc = 0; dc < 2; ++dc) {
      float4v bb = *(const float4v*)&qkv_b[h * 32 + dc * 16 + 4 * g];
#pragma unroll
      for (int ri = 0; ri < 4; ++ri)
#pragma unroll
        for (int j = 0; j < 4; ++j) acc[dc][ri][j] = bb[j] * (QSCALE * LOG2E);
    }
#pragma unroll 2
    for (int kt = 0; kt < 4; ++kt) {
      short8 af[4];
#pragma unroll
      for (int ri = 0; ri < 4; ++ri) af[ri] = LDA(kt, ri);
#pragma unroll
      for (int dc = 0; dc < 2; ++dc) {
        short8 w = LW(0, kt, dc);
#pragma unroll
        for (int ri = 0; ri < 4; ++ri) acc[dc][ri] = MFMA32(w, af[ri], acc[dc][ri], 0, 0, 0);
      }
    }
#pragma unroll
    for (int ri = 0; ri < 4; ++ri)
#pragma unroll
      for (int dc = 0; dc < 2; ++dc)
#pragma unroll
        for (int j = 0; j < 4; ++j) qp8[ri][4 * dc + j] = (short)f2b(acc[dc][ri][j]);
  }

  // ---------------- S' = K Q^T (K=32) + C, exp2, PV (K=32) -------------------
  const short* cs = &sm[8192 + h * 4096];
  float4v ot[2][4];
#pragma unroll
  for (int dt = 0; dt < 2; ++dt)
#pragma unroll
    for (int ri = 0; ri < 4; ++ri) { ot[dt][ri][0]=0.f; ot[dt][ri][1]=0.f; ot[dt][ri][2]=0.f; ot[dt][ri][3]=0.f; }
  float rs[4];
#pragma unroll
  for (int ri = 0; ri < 4; ++ri) {
    int row = 16 * ri + l15;  // token
    float sum = 0.f;
    short4v pb[4];
#pragma unroll
    for (int ci = 0; ci < 4; ++ci) {
      short4v cm = *(const short4v*)&cs[row * 64 + (((2 * ci + g2) ^ (row & 7)) << 3) + 4 * g1];
      float4v c;
#pragma unroll
      for (int j = 0; j < 4; ++j) c[j] = b2f((unsigned short)cm[j]);
      c = MFMA32(kp8[ci], qp8[ri], c, 0, 0, 0);
#pragma unroll
      for (int j = 0; j < 4; ++j) {
        float p = exp2f(c[j]);
        sum += p;
        pb[ci][j] = (short)f2b(p);
      }
    }
#pragma unroll
    for (int c2 = 0; c2 < 2; ++c2) {
      short8 pb8 = __builtin_shufflevector(pb[2 * c2], pb[2 * c2 + 1], 0, 1, 2, 3, 4, 5, 6, 7);
      ot[0][ri] = MFMA32(vp8[0][c2], pb8, ot[0][ri], 0, 0, 0);
      ot[1][ri] = MFMA32(vp8[1][c2], pb8, ot[1][ri], 0, 0, 0);
    }
    sum += __shfl_xor(sum, 16);
    sum += __shfl_xor(sum, 32);
    rs[ri] = __builtin_amdgcn_rcpf(sum);
  }

  __syncthreads();  // all waves done reading x from LDS
#pragma unroll
  for (int dt = 0; dt < 2; ++dt) {
    int ch = 4 * h + 2 * dt + g2;
#pragma unroll
    for (int ri = 0; ri < 4; ++ri) {
      int row = 16 * ri + l15;
      short4v pv;
#pragma unroll
      for (int j = 0; j < 4; ++j) pv[j] = (short)f2b(ot[dt][ri][j] * rs[ri]);
      *(short4v*)&sm[row * 128 + ((ch ^ (row & 7)) << 3) + 4 * g1] = pv;
    }
  }
  __syncthreads();

  // ---------------- output projection (kt looped), C init = proj_b -----------
  float4v po[2][4];
#pragma unroll
  for (int oc = 0; oc < 2; ++oc) {
    float4v pb4 = *(const float4v*)&proj_b[h * 32 + oc * 16 + 4 * g];
#pragma unroll
    for (int ri = 0; ri < 4; ++ri)
#pragma unroll
      for (int j = 0; j < 4; ++j) po[oc][ri][j] = pb4[j];
  }
#pragma unroll 2
  for (int kt = 0; kt < 4; ++kt) {
    short8 af[4];
#pragma unroll
    for (int ri = 0; ri < 4; ++ri) af[ri] = LDA(kt, ri);
#pragma unroll
    for (int oc = 0; oc < 2; ++oc) {
      short8 w = LW(49152, kt, oc);
#pragma unroll
      for (int ri = 0; ri < 4; ++ri)
        po[oc][ri] = MFMA32(w, af[ri], po[oc][ri], 0, 0, 0);
    }
  }
  float* ob = out + (size_t)b * 8192;
#pragma unroll
  for (int oc = 0; oc < 2; ++oc)
#pragma unroll
    for (int ri = 0; ri < 4; ++ri) {
      int row = 16 * ri + l15;
      float4 o = make_float4(po[oc][ri][0], po[oc][ri][1], po[oc][ri][2], po[oc][ri][3]);
      *(float4*)&ob[row * 128 + h * 32 + oc * 16 + 4 * g] = o;
    }
#undef LDA
#undef LW
}

extern "C" void kernel_launch(void* const* d_in, const int* in_sizes, int n_in,
                              void* d_out, int out_size, void* d_ws, size_t ws_size,
                              hipStream_t stream) {
  const float* x      = (const float*)d_in[0];
  const float* mask   = (const float*)d_in[1];
  const float* qkv_w  = (const float*)d_in[2];
  const float* qkv_b  = (const float*)d_in[3];
  const float* proj_w = (const float*)d_in[4];
  const float* proj_b = (const float*)d_in[5];
  const float* btab   = (const float*)d_in[6];
  const int*   ridx   = (const int*)d_in[7];
  unsigned short* ws  = (unsigned short*)d_ws;
  float* out = (float*)d_out;

  hipLaunchKernelGGL(prep_kernel, dim3(64), dim3(256), 0, stream, qkv_w, proj_w, btab, ridx, ws);
  hipLaunchKernelGGL(win_attn_kernel, dim3(8192), dim3(256), 0, stream,
                     x, mask, qkv_b, proj_b, ws, out);
}